// Round 2
// baseline (10088.807 us; speedup 1.0000x reference)
//
#include <hip/hip_runtime.h>
#include <hip/hip_bf16.h>
#include <math.h>

// Problem constants
#define BB 64
#define LL 200
#define NQ 1024
#define DD 256
#define HH 512
#define QQ 1024
#define G3 1536   // 3*H
#define BL 12800  // B*L
#define NBLK 256  // persistent GRU grid

// ---------------- workspace layout (in floats) ----------------
#define OFF_ACC   ((size_t)0)                    // 4 floats: [0]=creg_raw [1]=mse [2]=maskcnt
#define OFF_BAR   ((size_t)16)                   // barrier counter (64B-aligned), pad to 32
#define OFF_HA    ((size_t)32)                   // hA[2][512][64]
#define OFF_AQ    (OFF_HA + 65536)               // 1025*1536
#define OFF_DQ    (OFF_AQ + 1574400)
#define OFF_BQA   (OFF_DQ + 1574400)             // 2*1536
#define OFF_CQA   (OFF_BQA + 3072)
#define OFF_WSUM  (OFF_CQA + 3072)               // 1536*256
#define OFF_FCWT  (OFF_WSUM + 393216)            // 512*1024
#define OFF_M2    (OFF_FCWT + 524288)            // 1024*512
#define OFF_MB    (OFF_M2 + 524288)              // 1024
#define OFF_XG    (OFF_MB + 1024)                // 12800*1536  [t][b][1536] row=(t*64+b)
#define OFF_GRUT  (OFF_XG + 19660800)            // 200*64*512  [t][b][k]
#define OFF_QINT  (OFF_GRUT + 6553600)           // 12800 ints [B][L]
#define OFF_QAINT (OFF_QINT + 12800)
#define OFF_PIDF  (OFF_QAINT + 12800)
#define OFF_MVAL  (OFF_PIDF + 12800)
#define OFF_MC    (OFF_MVAL + 12800)
#define OFF_MI    (OFF_MC + 12800)
#define OFF_NMC   (OFF_MI + 12800)
#define OFF_AA    (OFF_NMC + 12800)
#define OFF_PREDS (OFF_AA + 12800)

__device__ __forceinline__ float wave_sum64(float v) {
    #pragma unroll
    for (int o = 32; o > 0; o >>= 1) v += __shfl_down(v, o, 64);
    return v;
}

// -------- meta: q, qa, pid per (b,t); c_reg accumulation --------
__global__ __launch_bounds__(256) void prep_meta(
    const int* __restrict__ q_data, const int* __restrict__ qa_data,
    const int* __restrict__ pid_data, const float* __restrict__ diff_parm,
    int* __restrict__ qint, int* __restrict__ qaint, float* __restrict__ pidf,
    float* __restrict__ acc)
{
    int r = blockIdx.x * 256 + threadIdx.x;
    float pp = 0.f;
    if (r < BL) {
        int q = q_data[r];
        qint[r] = q;
        qaint[r] = (qa_data[r] - q) / NQ;
        float pid = diff_parm[pid_data[r]];
        pidf[r] = pid;
        pp = pid * pid;
    }
    pp = wave_sum64(pp);
    __shared__ float sm[4];
    int lane = threadIdx.x & 63, w = threadIdx.x >> 6;
    if (lane == 0) sm[w] = pp;
    __syncthreads();
    if (threadIdx.x == 0) atomicAdd(&acc[0], sm[0] + sm[1] + sm[2] + sm[3]);
}

// -------- wsum[g,d] = w_ih[g,d] + w_ih[g,256+d] --------
__global__ __launch_bounds__(256) void wsum_kernel(const float* __restrict__ w_ih,
                                                   float* __restrict__ wsum)
{
    int g = blockIdx.x, d = threadIdx.x;   // 1536 blocks x 256
    wsum[(size_t)g * DD + d] = w_ih[(size_t)g * 2 * DD + d] + w_ih[(size_t)g * 2 * DD + DD + d];
}

// -------- transpose [R,C] -> [C,R] --------
__global__ __launch_bounds__(256) void transpose_kernel(const float* __restrict__ in,
                                                        float* __restrict__ out, int R, int C)
{
    __shared__ float tile[32][33];
    int r0 = blockIdx.y * 32, c0 = blockIdx.x * 32;
    int tx = threadIdx.x & 31, ty = threadIdx.x >> 5;  // ty 0..7
    #pragma unroll
    for (int i = 0; i < 32; i += 8) {
        int r = r0 + ty + i, c = c0 + tx;
        if (r < R && c < C) tile[ty + i][tx] = in[(size_t)r * C + c];
    }
    __syncthreads();
    #pragma unroll
    for (int i = 0; i < 32; i += 8) {
        int c = c0 + ty + i, r = r0 + tx;
        if (c < C && r < R) out[(size_t)c * R + r] = tile[tx][ty + i];
    }
}

// -------- generic NT GEMM: C[m,n] = sum_k A[m,k]*B[n,k] (+bias[n]) --------
__global__ __launch_bounds__(256) void gemm_nt(
    const float* __restrict__ A, int lda,
    const float* __restrict__ B, int ldb,
    float* __restrict__ C, int ldc,
    int M, int N, int K, const float* __restrict__ bias)
{
    __shared__ float As[16][65];
    __shared__ float Bs[16][65];
    const int bm = blockIdx.y * 64, bn = blockIdx.x * 64;
    const int tid = threadIdx.x;
    const int tx = tid & 15, ty = tid >> 4;
    float acc[4][4] = {};
    for (int k0 = 0; k0 < K; k0 += 16) {
        #pragma unroll
        for (int i = 0; i < 4; ++i) {
            int e = tid + i * 256;
            int mm = e >> 4, kk = e & 15;
            int m = bm + mm;
            As[kk][mm] = (m < M) ? A[(size_t)m * lda + k0 + kk] : 0.f;
            int n = bn + mm;
            Bs[kk][mm] = (n < N) ? B[(size_t)n * ldb + k0 + kk] : 0.f;
        }
        __syncthreads();
        #pragma unroll
        for (int kk = 0; kk < 16; ++kk) {
            float a[4], b[4];
            #pragma unroll
            for (int i = 0; i < 4; ++i) a[i] = As[kk][ty * 4 + i];
            #pragma unroll
            for (int j = 0; j < 4; ++j) b[j] = Bs[kk][tx * 4 + j];
            #pragma unroll
            for (int i = 0; i < 4; ++i)
                #pragma unroll
                for (int j = 0; j < 4; ++j) acc[i][j] += a[i] * b[j];
        }
        __syncthreads();
    }
    #pragma unroll
    for (int i = 0; i < 4; ++i) {
        int m = bm + ty * 4 + i;
        if (m >= M) continue;
        #pragma unroll
        for (int j = 0; j < 4; ++j) {
            int n = bn + tx * 4 + j;
            if (n >= N) continue;
            C[(size_t)m * ldc + n] = acc[i][j] + (bias ? bias[n] : 0.f);
        }
    }
}

// -------- mb[k] = sum_q matrix[k,q]*fc_b[q] --------
__global__ __launch_bounds__(256) void mb_kernel(const float* __restrict__ matrix,
                                                 const float* __restrict__ fc_b,
                                                 float* __restrict__ mb)
{
    int k = blockIdx.x;
    float s = 0.f;
    for (int q = threadIdx.x; q < QQ; q += 256) s += matrix[(size_t)k * QQ + q] * fc_b[q];
    s = wave_sum64(s);
    __shared__ float sm[4];
    int lane = threadIdx.x & 63, w = threadIdx.x >> 6;
    if (lane == 0) sm[w] = s;
    __syncthreads();
    if (threadIdx.x == 0) mb[k] = sm[0] + sm[1] + sm[2] + sm[3];
}

// -------- xg gather: xg[(t*64+b), g] = A_q[q,g]+B_qa[qa,g]+pid*(C_qa[qa,g]+D_q[q,g]) --------
__global__ __launch_bounds__(256) void xg_kernel(
    const float* __restrict__ Aq, const float* __restrict__ Bqa,
    const float* __restrict__ Cqa, const float* __restrict__ Dq,
    const int* __restrict__ qint, const int* __restrict__ qaint,
    const float* __restrict__ pidf, float* __restrict__ xg)
{
    int blk = blockIdx.x;              // t*64 + b
    int t = blk >> 6, b = blk & 63;
    int rm = b * LL + t;
    int q = qint[rm], qa = qaint[rm];
    float pid = pidf[rm];
    const float* aq = Aq + (size_t)q * G3;
    const float* dq = Dq + (size_t)q * G3;
    const float* bq = Bqa + (size_t)qa * G3;
    const float* cq = Cqa + (size_t)qa * G3;
    float* o = xg + (size_t)blk * G3;
    for (int g = threadIdx.x; g < G3; g += 256)
        o[g] = aq[g] + bq[g] + pid * (cq[g] + dq[g]);
}

// -------- persistent GRU: all 200 steps in one kernel, grid barrier per step --------
// 256 blocks x 256 threads. Block owns j0=2*bid, j0+1 (6 w_hh rows).
// Wave kq handles k in [kq*128, kq*128+128); lane = batch.
// w_hh values are wave-uniform -> scalar loads (hit sK$ after step 0).
__global__ __launch_bounds__(256) void gru_persist(
    const float* __restrict__ xg,      // [200*64][1536]
    const float* __restrict__ w_hh,    // [1536][512]
    const float* __restrict__ b_hh,    // [1536]
    float* __restrict__ hA,            // [2][512][64]
    float* __restrict__ gruT2,         // [200][64][512]
    unsigned int* __restrict__ bar)
{
    const int tid = threadIdx.x;
    const int b = tid & 63;
    const int kq = __builtin_amdgcn_readfirstlane(tid >> 6);   // wave id 0..3, uniform
    const int j0 = blockIdx.x * 2;
    __shared__ float part[4][6][64];

    const float* wp[6];
    #pragma unroll
    for (int g = 0; g < 3; ++g) {
        wp[g * 2 + 0] = w_hh + ((size_t)(g * HH + j0) * HH) + kq * 128;
        wp[g * 2 + 1] = w_hh + ((size_t)(g * HH + j0 + 1) * HH) + kq * 128;
    }
    const int jj = tid >> 6;           // used in epilogue (tid<128: 0 or 1)
    const int j = j0 + (jj & 1);
    const float bh_r = b_hh[j];
    const float bh_z = b_hh[HH + j];
    const float bh_n = b_hh[2 * HH + j];

    int cur = 0;
    for (int t = 0; t < LL; ++t) {
        const float* hc = hA + cur * (HH * BB) + kq * 128 * BB;
        float a0 = 0.f, a1 = 0.f, a2 = 0.f, a3 = 0.f, a4 = 0.f, a5 = 0.f;
        #pragma unroll 8
        for (int i = 0; i < 128; ++i) {
            float hv = hc[i * BB + b];
            a0 += wp[0][i] * hv;
            a1 += wp[1][i] * hv;
            a2 += wp[2][i] * hv;
            a3 += wp[3][i] * hv;
            a4 += wp[4][i] * hv;
            a5 += wp[5][i] * hv;
        }
        part[kq][0][b] = a0; part[kq][1][b] = a1; part[kq][2][b] = a2;
        part[kq][3][b] = a3; part[kq][4][b] = a4; part[kq][5][b] = a5;
        __syncthreads();
        if (tid < 128) {
            float sr = part[0][0 + jj][b] + part[1][0 + jj][b] + part[2][0 + jj][b] + part[3][0 + jj][b];
            float sz = part[0][2 + jj][b] + part[1][2 + jj][b] + part[2][2 + jj][b] + part[3][2 + jj][b];
            float sn = part[0][4 + jj][b] + part[1][4 + jj][b] + part[2][4 + jj][b] + part[3][4 + jj][b];
            const float* xgr = xg + ((size_t)t * BB + b) * G3;
            float xr = xgr[j], xz = xgr[HH + j], xn = xgr[2 * HH + j];
            float hprev = hA[cur * (HH * BB) + j * BB + b];
            float rg = 1.f / (1.f + expf(-(xr + sr + bh_r)));
            float zg = 1.f / (1.f + expf(-(xz + sz + bh_z)));
            float ng = tanhf(xn + rg * (sn + bh_n));
            float hn = (1.f - zg) * ng + zg * hprev;
            hA[(cur ^ 1) * (HH * BB) + j * BB + b] = hn;
            gruT2[((size_t)t * BB + b) * HH + j] = hn;
        }
        __syncthreads();   // drains vmcnt: epilogue stores globally visible
        if (tid == 0)
            __hip_atomic_fetch_add(bar, 1u, __ATOMIC_RELEASE, __HIP_MEMORY_SCOPE_AGENT);
        unsigned target = (unsigned)(t + 1) * NBLK;
        while (__hip_atomic_load(bar, __ATOMIC_ACQUIRE, __HIP_MEMORY_SCOPE_AGENT) < target)
            __builtin_amdgcn_s_sleep(2);
        __syncthreads();
        cur ^= 1;
    }
}

// -------- mvals[b,t] = threshold( dot(h_t, M2[q-1]) + mb[q-1] ) --------
// gruT2 is [t][b][k]: fully coalesced float4 loads, wave-per-b reduction.
__global__ __launch_bounds__(256) void mval_kernel(
    const float* __restrict__ gruT2,   // [200][64][512]
    const float* __restrict__ M2,      // [1024][512]
    const float* __restrict__ mb,
    const int* __restrict__ qint,      // [B][L]
    float* __restrict__ mval)          // [B][L]
{
    int t = blockIdx.x;
    int wave = threadIdx.x >> 6, l = threadIdx.x & 63;
    for (int ii = 0; ii < 16; ++ii) {
        int b = wave * 16 + ii;
        int q = qint[b * LL + t] - 1;
        const float4* hp = (const float4*)(gruT2 + ((size_t)t * BB + b) * HH);
        const float4* mp = (const float4*)(M2 + (size_t)q * HH);
        float4 h0 = hp[l], m0 = mp[l];
        float4 h1 = hp[64 + l], m1 = mp[64 + l];
        float acc = h0.x * m0.x + h0.y * m0.y + h0.z * m0.z + h0.w * m0.w
                  + h1.x * m1.x + h1.y * m1.y + h1.z * m1.z + h1.w * m1.w;
        acc = wave_sum64(acc);
        if (l == 0) {
            float s = acc + mb[q];
            mval[b * LL + t] = (s >= 0.4f) ? 1.0f : s;
        }
    }
}

// -------- per-(b,t) counting statistics --------
__global__ __launch_bounds__(256) void stats_kernel(
    const int* __restrict__ qint, const int* __restrict__ qaint,
    const float* __restrict__ mval,
    float* __restrict__ mc, float* __restrict__ mi,
    float* __restrict__ nmc, float* __restrict__ aa)
{
    int b = blockIdx.x, tid = threadIdx.x;
    __shared__ int qs[LL];
    __shared__ int qas[LL];
    __shared__ float mv[LL];
    if (tid < LL) {
        qs[tid] = qint[b * LL + tid];
        qas[tid] = qaint[b * LL + tid];
        mv[tid] = mval[b * LL + tid];
    }
    __syncthreads();
    int t = tid;
    if (t < LL) {
        int qt = qs[t];
        float smc = 0.f, smi = 0.f, snmc = 0.f, saa = 0.f;
        for (int k = 0; k <= t; ++k) {
            if (qs[k] == qt) {
                saa += 1.f;
                if (k < t) {
                    float mk = (mv[k] == 1.f) ? 1.f : 0.f;
                    float nk = (mv[k] == 0.f) ? 1.f : 0.f;
                    float a1 = (qas[k] == 1) ? 1.f : 0.f;
                    smc += a1 * mk;
                    smi += (1.f - a1) * mk;
                    snmc += (1.f - a1) * nk;
                }
            }
        }
        mc[b * LL + t] = smc;
        mi[b * LL + t] = smi;
        nmc[b * LL + t] = snmc;
        aa[b * LL + t] = saa;
    }
}

// -------- sequential DINA scan per batch --------
__global__ __launch_bounds__(256) void dina_kernel(
    const int* __restrict__ qint, const int* __restrict__ qaint,
    const float* __restrict__ mval,
    const float* __restrict__ mc, const float* __restrict__ mi,
    const float* __restrict__ nmc, const float* __restrict__ aa,
    float* __restrict__ preds)
{
    int b = blockIdx.x, tid = threadIdx.x;
    __shared__ float guess[QQ], slip[QQ];
    __shared__ float s_m[LL], s_mc[LL], s_mi[LL], s_nmc[LL], s_aa[LL];
    __shared__ int s_i[LL], s_qa[LL];
    for (int i = tid; i < QQ; i += 256) { guess[i] = 0.f; slip[i] = 0.f; }
    if (tid < LL) {
        s_m[tid] = mval[b * LL + tid];
        s_mc[tid] = mc[b * LL + tid];
        s_mi[tid] = mi[b * LL + tid];
        s_nmc[tid] = nmc[b * LL + tid];
        s_aa[tid] = aa[b * LL + tid];
        s_i[tid] = qint[b * LL + tid] - 1;
        s_qa[tid] = qaint[b * LL + tid];
    }
    __syncthreads();
    if (tid == 0) {
        for (int t = 0; t < LL; ++t) {
            int i = s_i[t];
            float m = s_m[t];
            int qa = s_qa[t];
            float aat = s_aa[t];
            float g_upd = (m == 1.f) ? s_mc[t] / aat
                          : ((qa == 0) ? 1.f - s_nmc[t] / aat : s_nmc[t] / aat);
            bool us = (m == 1.f) && (qa == 0);
            float ng = us ? guess[i] : g_upd;
            float ns = us ? s_mi[t] / aat : slip[i];
            guess[i] = ng;
            slip[i] = ns;
            preds[b * LL + t] = (1.f - ns) * (m * ng + (1.f - ns) * (1.f - m));
        }
    }
}

// -------- masked MSE + sigmoid outputs --------
__global__ __launch_bounds__(256) void loss_kernel(
    const float* __restrict__ preds, const float* __restrict__ target,
    float* __restrict__ out, float* __restrict__ acc)
{
    int r = blockIdx.x * 256 + threadIdx.x;
    float lm = 0.f, lc = 0.f;
    if (r < BL) {
        float p = preds[r], lab = target[r];
        float msk = (lab > -0.9f) ? 1.f : 0.f;
        float d = p - lab;
        lm = d * d * msk;
        lc = msk;
        out[1 + r] = 1.f / (1.f + expf(-p));
    }
    lm = wave_sum64(lm);
    lc = wave_sum64(lc);
    __shared__ float sm[4], sc[4];
    int lane = threadIdx.x & 63, w = threadIdx.x >> 6;
    if (lane == 0) { sm[w] = lm; sc[w] = lc; }
    __syncthreads();
    if (threadIdx.x == 0) {
        atomicAdd(&acc[1], sm[0] + sm[1] + sm[2] + sm[3]);
        atomicAdd(&acc[2], sc[0] + sc[1] + sc[2] + sc[3]);
    }
}

__global__ void final_kernel(const float* __restrict__ acc, float* __restrict__ out)
{
    out[0] = acc[1] + acc[0] * 1e-5f;
    out[1 + BL] = acc[2];
}

extern "C" void kernel_launch(void* const* d_in, const int* in_sizes, int n_in,
                              void* d_out, int out_size, void* d_ws, size_t ws_size,
                              hipStream_t stream) {
    const int* q_data = (const int*)d_in[0];
    const int* qa_data = (const int*)d_in[1];
    const int* pid_data = (const int*)d_in[2];
    const float* matrix = (const float*)d_in[3];
    const float* target = (const float*)d_in[4];
    const float* q_emb = (const float*)d_in[5];
    const float* qa_emb = (const float*)d_in[6];
    const float* q_emb_diff = (const float*)d_in[7];
    const float* qa_emb_diff = (const float*)d_in[8];
    const float* diff_parm = (const float*)d_in[9];
    const float* w_ih = (const float*)d_in[10];
    const float* w_hh = (const float*)d_in[11];
    const float* b_ih = (const float*)d_in[12];
    const float* b_hh = (const float*)d_in[13];
    const float* fc_w = (const float*)d_in[14];
    const float* fc_b = (const float*)d_in[15];
    float* out = (float*)d_out;
    float* W = (float*)d_ws;

    float* acc = W + OFF_ACC;
    unsigned int* bar = (unsigned int*)(W + OFF_BAR);
    float* hA = W + OFF_HA;
    float* Aq = W + OFF_AQ;
    float* Dq = W + OFF_DQ;
    float* Bqa = W + OFF_BQA;
    float* Cqa = W + OFF_CQA;
    float* wsum = W + OFF_WSUM;
    float* fcwT = W + OFF_FCWT;
    float* M2 = W + OFF_M2;
    float* mb = W + OFF_MB;
    float* xg = W + OFF_XG;
    float* gruT2 = W + OFF_GRUT;
    int* qint = (int*)(W + OFF_QINT);
    int* qaint = (int*)(W + OFF_QAINT);
    float* pidf = W + OFF_PIDF;
    float* mval = W + OFF_MVAL;
    float* mc = W + OFF_MC;
    float* mi = W + OFF_MI;
    float* nmc = W + OFF_NMC;
    float* aa = W + OFF_AA;
    float* preds = W + OFF_PREDS;

    // zero accumulators + barrier + both h buffers (contiguous at start of ws)
    hipMemsetAsync(W, 0, (32 + 2 * HH * BB) * sizeof(float), stream);

    prep_meta<<<50, 256, 0, stream>>>(q_data, qa_data, pid_data, diff_parm,
                                      qint, qaint, pidf, acc);
    wsum_kernel<<<G3, 256, 0, stream>>>(w_ih, wsum);
    transpose_kernel<<<dim3(16, 32), 256, 0, stream>>>(fc_w, fcwT, QQ, HH);

    gemm_nt<<<dim3(24, 1), 256, 0, stream>>>(qa_emb, DD, w_ih, 2 * DD, Bqa, G3, 2, G3, DD, b_ih);
    gemm_nt<<<dim3(24, 1), 256, 0, stream>>>(qa_emb_diff, DD, w_ih, 2 * DD, Cqa, G3, 2, G3, DD, nullptr);
    gemm_nt<<<dim3(24, 17), 256, 0, stream>>>(q_emb, DD, wsum, DD, Aq, G3, NQ + 1, G3, DD, nullptr);
    gemm_nt<<<dim3(24, 17), 256, 0, stream>>>(q_emb_diff, DD, w_ih + DD, 2 * DD, Dq, G3, NQ + 1, G3, DD, nullptr);
    gemm_nt<<<dim3(8, 16), 256, 0, stream>>>(matrix, QQ, fcwT, QQ, M2, HH, QQ, HH, QQ, nullptr);
    mb_kernel<<<QQ, 256, 0, stream>>>(matrix, fc_b, mb);

    xg_kernel<<<BL, 256, 0, stream>>>(Aq, Bqa, Cqa, Dq, qint, qaint, pidf, xg);

    gru_persist<<<NBLK, 256, 0, stream>>>(xg, w_hh, b_hh, hA, gruT2, bar);

    mval_kernel<<<LL, 256, 0, stream>>>(gruT2, M2, mb, qint, mval);
    stats_kernel<<<BB, 256, 0, stream>>>(qint, qaint, mval, mc, mi, nmc, aa);
    dina_kernel<<<BB, 256, 0, stream>>>(qint, qaint, mval, mc, mi, nmc, aa, preds);
    loss_kernel<<<50, 256, 0, stream>>>(preds, target, out, acc);
    final_kernel<<<1, 1, 0, stream>>>(acc, out);
}

// Round 3
// 2744.118 us; speedup vs baseline: 3.6765x; 3.6765x over previous
//
#include <hip/hip_runtime.h>
#include <hip/hip_bf16.h>
#include <math.h>

// Problem constants
#define BB 64
#define LL 200
#define NQ 1024
#define DD 256
#define HH 512
#define QQ 1024
#define G3 1536   // 3*H
#define BL 12800  // B*L
#define GBLK 128  // persistent GRU grid (<= 256 CUs -> co-resident)
#define JPB 4     // j-units per block

// ---------------- workspace layout (in floats) ----------------
#define OFF_ACC   ((size_t)0)                    // [0]=creg_raw [1]=mse [2]=maskcnt
#define OFF_CELLS ((size_t)16)                   // 16 barrier cells, 64B apart (256 uints)
#define OFF_HA    ((size_t)288)                  // hA[2][512][64] (64B aligned)
#define OFF_AQ    (OFF_HA + 65536)               // 1025*1536
#define OFF_DQ    (OFF_AQ + 1574400)
#define OFF_BQA   (OFF_DQ + 1574400)             // 2*1536
#define OFF_CQA   (OFF_BQA + 3072)
#define OFF_WSUM  (OFF_CQA + 3072)               // 1536*256
#define OFF_FCWT  (OFF_WSUM + 393216)            // 512*1024
#define OFF_M2    (OFF_FCWT + 524288)            // 1024*512
#define OFF_MB    (OFF_M2 + 524288)              // 1024
#define OFF_XG    (OFF_MB + 1024)                // [t][b][1536]
#define OFF_GRUT  (OFF_XG + 19660800)            // [t][b][k]
#define OFF_QINT  (OFF_GRUT + 6553600)           // 12800 ints [B][L]
#define OFF_QAINT (OFF_QINT + 12800)
#define OFF_PIDF  (OFF_QAINT + 12800)
#define OFF_MVAL  (OFF_PIDF + 12800)
#define OFF_MC    (OFF_MVAL + 12800)
#define OFF_MI    (OFF_MC + 12800)
#define OFF_NMC   (OFF_MI + 12800)
#define OFF_AA    (OFF_NMC + 12800)
#define OFF_PREDS (OFF_AA + 12800)

__device__ __forceinline__ float wave_sum64(float v) {
    #pragma unroll
    for (int o = 32; o > 0; o >>= 1) v += __shfl_down(v, o, 64);
    return v;
}

// LLC-coherent (device-scope, relaxed => sc0/sc1, NO wbl2/inv) helpers
__device__ __forceinline__ float llc_load(const float* p) {
    return __hip_atomic_load(p, __ATOMIC_RELAXED, __HIP_MEMORY_SCOPE_AGENT);
}
__device__ __forceinline__ void llc_store(float* p, float v) {
    __hip_atomic_store(p, v, __ATOMIC_RELAXED, __HIP_MEMORY_SCOPE_AGENT);
}

// -------- meta: q, qa, pid per (b,t); c_reg accumulation --------
__global__ __launch_bounds__(256) void prep_meta(
    const int* __restrict__ q_data, const int* __restrict__ qa_data,
    const int* __restrict__ pid_data, const float* __restrict__ diff_parm,
    int* __restrict__ qint, int* __restrict__ qaint, float* __restrict__ pidf,
    float* __restrict__ acc)
{
    int r = blockIdx.x * 256 + threadIdx.x;
    float pp = 0.f;
    if (r < BL) {
        int q = q_data[r];
        qint[r] = q;
        qaint[r] = (qa_data[r] - q) / NQ;
        float pid = diff_parm[pid_data[r]];
        pidf[r] = pid;
        pp = pid * pid;
    }
    pp = wave_sum64(pp);
    __shared__ float sm[4];
    int lane = threadIdx.x & 63, w = threadIdx.x >> 6;
    if (lane == 0) sm[w] = pp;
    __syncthreads();
    if (threadIdx.x == 0) atomicAdd(&acc[0], sm[0] + sm[1] + sm[2] + sm[3]);
}

// -------- wsum[g,d] = w_ih[g,d] + w_ih[g,256+d] --------
__global__ __launch_bounds__(256) void wsum_kernel(const float* __restrict__ w_ih,
                                                   float* __restrict__ wsum)
{
    int g = blockIdx.x, d = threadIdx.x;
    wsum[(size_t)g * DD + d] = w_ih[(size_t)g * 2 * DD + d] + w_ih[(size_t)g * 2 * DD + DD + d];
}

// -------- transpose [R,C] -> [C,R] --------
__global__ __launch_bounds__(256) void transpose_kernel(const float* __restrict__ in,
                                                        float* __restrict__ out, int R, int C)
{
    __shared__ float tile[32][33];
    int r0 = blockIdx.y * 32, c0 = blockIdx.x * 32;
    int tx = threadIdx.x & 31, ty = threadIdx.x >> 5;
    #pragma unroll
    for (int i = 0; i < 32; i += 8) {
        int r = r0 + ty + i, c = c0 + tx;
        if (r < R && c < C) tile[ty + i][tx] = in[(size_t)r * C + c];
    }
    __syncthreads();
    #pragma unroll
    for (int i = 0; i < 32; i += 8) {
        int c = c0 + ty + i, r = r0 + tx;
        if (c < C && r < R) out[(size_t)c * R + r] = tile[tx][ty + i];
    }
}

// -------- NT GEMM with register prefetch: C[m,n] = sum_k A[m,k]*B[n,k] (+bias[n]) --------
__global__ __launch_bounds__(256) void gemm_nt(
    const float* __restrict__ A, int lda,
    const float* __restrict__ B, int ldb,
    float* __restrict__ C, int ldc,
    int M, int N, int K, const float* __restrict__ bias)
{
    __shared__ float As[16][65];
    __shared__ float Bs[16][65];
    const int bm = blockIdx.y * 64, bn = blockIdx.x * 64;
    const int tid = threadIdx.x;
    const int tx = tid & 15, ty = tid >> 4;
    const int mm = tid >> 4, kk = tid & 15;
    float acc[4][4] = {};
    float ar[4], br[4];
    #pragma unroll
    for (int i = 0; i < 4; ++i) {
        int m = bm + mm + 16 * i;
        ar[i] = (m < M) ? A[(size_t)m * lda + kk] : 0.f;
        int n = bn + mm + 16 * i;
        br[i] = (n < N) ? B[(size_t)n * ldb + kk] : 0.f;
    }
    for (int k0 = 0; k0 < K; k0 += 16) {
        #pragma unroll
        for (int i = 0; i < 4; ++i) { As[kk][mm + 16 * i] = ar[i]; Bs[kk][mm + 16 * i] = br[i]; }
        __syncthreads();
        int kn = k0 + 16;
        if (kn < K) {
            #pragma unroll
            for (int i = 0; i < 4; ++i) {
                int m = bm + mm + 16 * i;
                ar[i] = (m < M) ? A[(size_t)m * lda + kn + kk] : 0.f;
                int n = bn + mm + 16 * i;
                br[i] = (n < N) ? B[(size_t)n * ldb + kn + kk] : 0.f;
            }
        }
        #pragma unroll
        for (int kq = 0; kq < 16; ++kq) {
            float a[4], b[4];
            #pragma unroll
            for (int i = 0; i < 4; ++i) a[i] = As[kq][ty * 4 + i];
            #pragma unroll
            for (int j = 0; j < 4; ++j) b[j] = Bs[kq][tx * 4 + j];
            #pragma unroll
            for (int i = 0; i < 4; ++i)
                #pragma unroll
                for (int j = 0; j < 4; ++j) acc[i][j] += a[i] * b[j];
        }
        __syncthreads();
    }
    #pragma unroll
    for (int i = 0; i < 4; ++i) {
        int m = bm + ty * 4 + i;
        if (m >= M) continue;
        #pragma unroll
        for (int j = 0; j < 4; ++j) {
            int n = bn + tx * 4 + j;
            if (n >= N) continue;
            C[(size_t)m * ldc + n] = acc[i][j] + (bias ? bias[n] : 0.f);
        }
    }
}

// -------- dual-batched NT GEMM (two independent problems, z picks) --------
__global__ __launch_bounds__(256) void gemm_nt_dual(
    const float* __restrict__ A0, const float* __restrict__ A1, int lda,
    const float* __restrict__ B0, const float* __restrict__ B1, int ldb0, int ldb1,
    float* __restrict__ C0, float* __restrict__ C1, int ldc,
    int M, int N, int K,
    const float* __restrict__ bias0, const float* __restrict__ bias1)
{
    const int z = blockIdx.z;
    const float* A = z ? A1 : A0;
    const float* B = z ? B1 : B0;
    float* C = z ? C1 : C0;
    const int ldb = z ? ldb1 : ldb0;
    const float* bias = z ? bias1 : bias0;

    __shared__ float As[16][65];
    __shared__ float Bs[16][65];
    const int bm = blockIdx.y * 64, bn = blockIdx.x * 64;
    const int tid = threadIdx.x;
    const int tx = tid & 15, ty = tid >> 4;
    const int mm = tid >> 4, kk = tid & 15;
    float acc[4][4] = {};
    float ar[4], br[4];
    #pragma unroll
    for (int i = 0; i < 4; ++i) {
        int m = bm + mm + 16 * i;
        ar[i] = (m < M) ? A[(size_t)m * lda + kk] : 0.f;
        int n = bn + mm + 16 * i;
        br[i] = (n < N) ? B[(size_t)n * ldb + kk] : 0.f;
    }
    for (int k0 = 0; k0 < K; k0 += 16) {
        #pragma unroll
        for (int i = 0; i < 4; ++i) { As[kk][mm + 16 * i] = ar[i]; Bs[kk][mm + 16 * i] = br[i]; }
        __syncthreads();
        int kn = k0 + 16;
        if (kn < K) {
            #pragma unroll
            for (int i = 0; i < 4; ++i) {
                int m = bm + mm + 16 * i;
                ar[i] = (m < M) ? A[(size_t)m * lda + kn + kk] : 0.f;
                int n = bn + mm + 16 * i;
                br[i] = (n < N) ? B[(size_t)n * ldb + kn + kk] : 0.f;
            }
        }
        #pragma unroll
        for (int kq = 0; kq < 16; ++kq) {
            float a[4], b[4];
            #pragma unroll
            for (int i = 0; i < 4; ++i) a[i] = As[kq][ty * 4 + i];
            #pragma unroll
            for (int j = 0; j < 4; ++j) b[j] = Bs[kq][tx * 4 + j];
            #pragma unroll
            for (int i = 0; i < 4; ++i)
                #pragma unroll
                for (int j = 0; j < 4; ++j) acc[i][j] += a[i] * b[j];
        }
        __syncthreads();
    }
    #pragma unroll
    for (int i = 0; i < 4; ++i) {
        int m = bm + ty * 4 + i;
        if (m >= M) continue;
        #pragma unroll
        for (int j = 0; j < 4; ++j) {
            int n = bn + tx * 4 + j;
            if (n >= N) continue;
            C[(size_t)m * ldc + n] = acc[i][j] + (bias ? bias[n] : 0.f);
        }
    }
}

// -------- mb[k] = sum_q matrix[k,q]*fc_b[q] --------
__global__ __launch_bounds__(256) void mb_kernel(const float* __restrict__ matrix,
                                                 const float* __restrict__ fc_b,
                                                 float* __restrict__ mb)
{
    int k = blockIdx.x;
    float s = 0.f;
    for (int q = threadIdx.x; q < QQ; q += 256) s += matrix[(size_t)k * QQ + q] * fc_b[q];
    s = wave_sum64(s);
    __shared__ float sm[4];
    int lane = threadIdx.x & 63, w = threadIdx.x >> 6;
    if (lane == 0) sm[w] = s;
    __syncthreads();
    if (threadIdx.x == 0) mb[k] = sm[0] + sm[1] + sm[2] + sm[3];
}

// -------- xg gather --------
__global__ __launch_bounds__(256) void xg_kernel(
    const float* __restrict__ Aq, const float* __restrict__ Bqa,
    const float* __restrict__ Cqa, const float* __restrict__ Dq,
    const int* __restrict__ qint, const int* __restrict__ qaint,
    const float* __restrict__ pidf, float* __restrict__ xg)
{
    int blk = blockIdx.x;              // t*64 + b
    int t = blk >> 6, b = blk & 63;
    int rm = b * LL + t;
    int q = qint[rm], qa = qaint[rm];
    float pid = pidf[rm];
    const float* aq = Aq + (size_t)q * G3;
    const float* dq = Dq + (size_t)q * G3;
    const float* bq = Bqa + (size_t)qa * G3;
    const float* cq = Cqa + (size_t)qa * G3;
    float* o = xg + (size_t)blk * G3;
    for (int g = threadIdx.x; g < G3; g += 256)
        o[g] = aq[g] + bq[g] + pid * (cq[g] + dq[g]);
}

// -------- persistent GRU, LLC-coherent h exchange, fence-free barrier --------
// 128 blocks x 512 threads. Block owns 4 j-units (12 w_hh rows, staged in LDS once).
// Wave wv covers k in [wv*64, wv*64+64); lane = batch.
// h ping-pong via relaxed agent-scope atomics (sc0/sc1 -> LLC coherent, no wbl2/inv).
// Ordering: __syncthreads() drains vmcnt before s_barrier (compiler-guaranteed),
// so all h stores are LLC-visible before thread 0's barrier arrive.
__global__ __launch_bounds__(512) void gru_persist(
    const float* __restrict__ xg,      // [200*64][1536]
    const float* __restrict__ w_hh,    // [1536][512]
    const float* __restrict__ b_hh,    // [1536]
    float* __restrict__ hA,            // [2][512][64]
    float* __restrict__ gruT2,         // [200][64][512]
    unsigned int* __restrict__ cells)  // 16 cells, 64B apart
{
    __shared__ float ws[12][HH];       // 24 KB: this block's 12 w_hh rows
    __shared__ float part[8][12][64];  // 24 KB: per-wave partials
    __shared__ float sums[12][64];     // 3 KB
    const int tid = threadIdx.x;
    const int bid = blockIdx.x;
    const int j0 = bid * JPB;

    for (int i = tid; i < 12 * HH; i += 512) {
        int r = i >> 9, k = i & 511;
        ws[r][k] = w_hh[((size_t)((r >> 2) * HH + j0 + (r & 3))) * HH + k];
    }
    const int wv = tid >> 6;
    const int lane = tid & 63;
    const int kb = wv * 64;
    const int jj = wv & 3;             // epilogue row (tid<256)
    const int ej = j0 + jj;
    float bhr = 0.f, bhz = 0.f, bhn = 0.f;
    if (tid < 256) { bhr = b_hh[ej]; bhz = b_hh[HH + ej]; bhn = b_hh[2 * HH + ej]; }
    __syncthreads();

    int cur = 0;
    for (int t = 0; t < LL; ++t) {
        const float* hcur = hA + (size_t)cur * (HH * BB);
        float acc[12];
        #pragma unroll
        for (int r = 0; r < 12; ++r) acc[r] = 0.f;
        const float* hbase = hcur + lane;
        #pragma unroll 4
        for (int c = 0; c < 16; ++c) {
            int k = kb + c * 4;
            float h0 = llc_load(hbase + (size_t)(k + 0) * BB);
            float h1 = llc_load(hbase + (size_t)(k + 1) * BB);
            float h2 = llc_load(hbase + (size_t)(k + 2) * BB);
            float h3 = llc_load(hbase + (size_t)(k + 3) * BB);
            #pragma unroll
            for (int r = 0; r < 12; ++r) {
                const float4 w4 = *(const float4*)&ws[r][k];
                acc[r] += w4.x * h0 + w4.y * h1 + w4.z * h2 + w4.w * h3;
            }
        }
        #pragma unroll
        for (int r = 0; r < 12; ++r) part[wv][r][lane] = acc[r];
        // prefetch epilogue inputs (independent of the reduction)
        float xr = 0.f, xz = 0.f, xn = 0.f, hprev = 0.f;
        if (tid < 256) {
            const float* xgr = xg + ((size_t)t * BB + lane) * G3;
            xr = xgr[ej]; xz = xgr[HH + ej]; xn = xgr[2 * HH + ej];
            hprev = llc_load(hcur + (size_t)ej * BB + lane);
        }
        __syncthreads();
        for (int idx = tid; idx < 768; idx += 512) {
            int r = idx >> 6, b = idx & 63;
            sums[r][b] = part[0][r][b] + part[1][r][b] + part[2][r][b] + part[3][r][b]
                       + part[4][r][b] + part[5][r][b] + part[6][r][b] + part[7][r][b];
        }
        __syncthreads();
        if (tid < 256) {
            float sr = sums[jj][lane], sz = sums[4 + jj][lane], sn = sums[8 + jj][lane];
            float rg = 1.f / (1.f + expf(-(xr + sr + bhr)));
            float zg = 1.f / (1.f + expf(-(xz + sz + bhz)));
            float ng = tanhf(xn + rg * (sn + bhn));
            float hn = (1.f - zg) * ng + zg * hprev;
            llc_store(hA + (size_t)(cur ^ 1) * (HH * BB) + (size_t)ej * BB + lane, hn);
            gruT2[((size_t)t * BB + lane) * HH + ej] = hn;
        }
        __syncthreads();   // drains vmcnt: h stores LLC-visible before arrive
        if (tid == 0) {
            __hip_atomic_fetch_add(&cells[(bid & 15) * 16], 1u,
                                   __ATOMIC_RELAXED, __HIP_MEMORY_SCOPE_AGENT);
            const unsigned want = (unsigned)(t + 1) * GBLK;
            for (;;) {
                unsigned s = 0;
                #pragma unroll
                for (int c2 = 0; c2 < 16; ++c2)
                    s += __hip_atomic_load(&cells[c2 * 16],
                                           __ATOMIC_RELAXED, __HIP_MEMORY_SCOPE_AGENT);
                if (s >= want) break;
                __builtin_amdgcn_s_sleep(1);
            }
        }
        __syncthreads();
        cur ^= 1;
    }
}

// -------- mvals[b,t] = threshold( dot(h_t, M2[q-1]) + mb[q-1] ) --------
__global__ __launch_bounds__(256) void mval_kernel(
    const float* __restrict__ gruT2,   // [200][64][512]
    const float* __restrict__ M2,      // [1024][512]
    const float* __restrict__ mb,
    const int* __restrict__ qint,      // [B][L]
    float* __restrict__ mval)          // [B][L]
{
    int t = blockIdx.x;
    int wave = threadIdx.x >> 6, l = threadIdx.x & 63;
    for (int ii = 0; ii < 16; ++ii) {
        int b = wave * 16 + ii;
        int q = qint[b * LL + t] - 1;
        const float4* hp = (const float4*)(gruT2 + ((size_t)t * BB + b) * HH);
        const float4* mp = (const float4*)(M2 + (size_t)q * HH);
        float4 h0 = hp[l], m0 = mp[l];
        float4 h1 = hp[64 + l], m1 = mp[64 + l];
        float acc = h0.x * m0.x + h0.y * m0.y + h0.z * m0.z + h0.w * m0.w
                  + h1.x * m1.x + h1.y * m1.y + h1.z * m1.z + h1.w * m1.w;
        acc = wave_sum64(acc);
        if (l == 0) {
            float s = acc + mb[q];
            mval[b * LL + t] = (s >= 0.4f) ? 1.0f : s;
        }
    }
}

// -------- per-(b,t) counting statistics --------
__global__ __launch_bounds__(256) void stats_kernel(
    const int* __restrict__ qint, const int* __restrict__ qaint,
    const float* __restrict__ mval,
    float* __restrict__ mc, float* __restrict__ mi,
    float* __restrict__ nmc, float* __restrict__ aa)
{
    int b = blockIdx.x, tid = threadIdx.x;
    __shared__ int qs[LL];
    __shared__ int qas[LL];
    __shared__ float mv[LL];
    if (tid < LL) {
        qs[tid] = qint[b * LL + tid];
        qas[tid] = qaint[b * LL + tid];
        mv[tid] = mval[b * LL + tid];
    }
    __syncthreads();
    int t = tid;
    if (t < LL) {
        int qt = qs[t];
        float smc = 0.f, smi = 0.f, snmc = 0.f, saa = 0.f;
        for (int k = 0; k <= t; ++k) {
            if (qs[k] == qt) {
                saa += 1.f;
                if (k < t) {
                    float mk = (mv[k] == 1.f) ? 1.f : 0.f;
                    float nk = (mv[k] == 0.f) ? 1.f : 0.f;
                    float a1 = (qas[k] == 1) ? 1.f : 0.f;
                    smc += a1 * mk;
                    smi += (1.f - a1) * mk;
                    snmc += (1.f - a1) * nk;
                }
            }
        }
        mc[b * LL + t] = smc;
        mi[b * LL + t] = smi;
        nmc[b * LL + t] = snmc;
        aa[b * LL + t] = saa;
    }
}

// -------- sequential DINA scan per batch --------
__global__ __launch_bounds__(256) void dina_kernel(
    const int* __restrict__ qint, const int* __restrict__ qaint,
    const float* __restrict__ mval,
    const float* __restrict__ mc, const float* __restrict__ mi,
    const float* __restrict__ nmc, const float* __restrict__ aa,
    float* __restrict__ preds)
{
    int b = blockIdx.x, tid = threadIdx.x;
    __shared__ float guess[QQ], slip[QQ];
    __shared__ float s_m[LL], s_mc[LL], s_mi[LL], s_nmc[LL], s_aa[LL];
    __shared__ int s_i[LL], s_qa[LL];
    for (int i = tid; i < QQ; i += 256) { guess[i] = 0.f; slip[i] = 0.f; }
    if (tid < LL) {
        s_m[tid] = mval[b * LL + tid];
        s_mc[tid] = mc[b * LL + tid];
        s_mi[tid] = mi[b * LL + tid];
        s_nmc[tid] = nmc[b * LL + tid];
        s_aa[tid] = aa[b * LL + tid];
        s_i[tid] = qint[b * LL + tid] - 1;
        s_qa[tid] = qaint[b * LL + tid];
    }
    __syncthreads();
    if (tid == 0) {
        for (int t = 0; t < LL; ++t) {
            int i = s_i[t];
            float m = s_m[t];
            int qa = s_qa[t];
            float aat = s_aa[t];
            float g_upd = (m == 1.f) ? s_mc[t] / aat
                          : ((qa == 0) ? 1.f - s_nmc[t] / aat : s_nmc[t] / aat);
            bool us = (m == 1.f) && (qa == 0);
            float ng = us ? guess[i] : g_upd;
            float ns = us ? s_mi[t] / aat : slip[i];
            guess[i] = ng;
            slip[i] = ns;
            preds[b * LL + t] = (1.f - ns) * (m * ng + (1.f - ns) * (1.f - m));
        }
    }
}

// -------- masked MSE + sigmoid outputs --------
__global__ __launch_bounds__(256) void loss_kernel(
    const float* __restrict__ preds, const float* __restrict__ target,
    float* __restrict__ out, float* __restrict__ acc)
{
    int r = blockIdx.x * 256 + threadIdx.x;
    float lm = 0.f, lc = 0.f;
    if (r < BL) {
        float p = preds[r], lab = target[r];
        float msk = (lab > -0.9f) ? 1.f : 0.f;
        float d = p - lab;
        lm = d * d * msk;
        lc = msk;
        out[1 + r] = 1.f / (1.f + expf(-p));
    }
    lm = wave_sum64(lm);
    lc = wave_sum64(lc);
    __shared__ float sm[4], sc[4];
    int lane = threadIdx.x & 63, w = threadIdx.x >> 6;
    if (lane == 0) { sm[w] = lm; sc[w] = lc; }
    __syncthreads();
    if (threadIdx.x == 0) {
        atomicAdd(&acc[1], sm[0] + sm[1] + sm[2] + sm[3]);
        atomicAdd(&acc[2], sc[0] + sc[1] + sc[2] + sc[3]);
    }
}

__global__ void final_kernel(const float* __restrict__ acc, float* __restrict__ out)
{
    out[0] = acc[1] + acc[0] * 1e-5f;
    out[1 + BL] = acc[2];
}

extern "C" void kernel_launch(void* const* d_in, const int* in_sizes, int n_in,
                              void* d_out, int out_size, void* d_ws, size_t ws_size,
                              hipStream_t stream) {
    const int* q_data = (const int*)d_in[0];
    const int* qa_data = (const int*)d_in[1];
    const int* pid_data = (const int*)d_in[2];
    const float* matrix = (const float*)d_in[3];
    const float* target = (const float*)d_in[4];
    const float* q_emb = (const float*)d_in[5];
    const float* qa_emb = (const float*)d_in[6];
    const float* q_emb_diff = (const float*)d_in[7];
    const float* qa_emb_diff = (const float*)d_in[8];
    const float* diff_parm = (const float*)d_in[9];
    const float* w_ih = (const float*)d_in[10];
    const float* w_hh = (const float*)d_in[11];
    const float* b_ih = (const float*)d_in[12];
    const float* b_hh = (const float*)d_in[13];
    const float* fc_w = (const float*)d_in[14];
    const float* fc_b = (const float*)d_in[15];
    float* out = (float*)d_out;
    float* W = (float*)d_ws;

    float* acc = W + OFF_ACC;
    unsigned int* cells = (unsigned int*)(W + OFF_CELLS);
    float* hA = W + OFF_HA;
    float* Aq = W + OFF_AQ;
    float* Dq = W + OFF_DQ;
    float* Bqa = W + OFF_BQA;
    float* Cqa = W + OFF_CQA;
    float* wsum = W + OFF_WSUM;
    float* fcwT = W + OFF_FCWT;
    float* M2 = W + OFF_M2;
    float* mb = W + OFF_MB;
    float* xg = W + OFF_XG;
    float* gruT2 = W + OFF_GRUT;
    int* qint = (int*)(W + OFF_QINT);
    int* qaint = (int*)(W + OFF_QAINT);
    float* pidf = W + OFF_PIDF;
    float* mval = W + OFF_MVAL;
    float* mc = W + OFF_MC;
    float* mi = W + OFF_MI;
    float* nmc = W + OFF_NMC;
    float* aa = W + OFF_AA;
    float* preds = W + OFF_PREDS;

    // zero accumulators + barrier cells + both h buffers (contiguous at ws start)
    hipMemsetAsync(W, 0, (OFF_HA + 2 * HH * BB) * sizeof(float), stream);

    prep_meta<<<50, 256, 0, stream>>>(q_data, qa_data, pid_data, diff_parm,
                                      qint, qaint, pidf, acc);
    wsum_kernel<<<G3, 256, 0, stream>>>(w_ih, wsum);
    transpose_kernel<<<dim3(16, 32), 256, 0, stream>>>(fc_w, fcwT, QQ, HH);

    // Bqa/Cqa batched
    gemm_nt_dual<<<dim3(24, 1, 2), 256, 0, stream>>>(
        qa_emb, qa_emb_diff, DD, w_ih, w_ih, 2 * DD, 2 * DD,
        Bqa, Cqa, G3, 2, G3, DD, b_ih, nullptr);
    // Aq/Dq batched
    gemm_nt_dual<<<dim3(24, 17, 2), 256, 0, stream>>>(
        q_emb, q_emb_diff, DD, wsum, w_ih + DD, DD, 2 * DD,
        Aq, Dq, G3, NQ + 1, G3, DD, nullptr, nullptr);
    // M2 = matrix . fc_w  (via fcwT, NT form)
    gemm_nt<<<dim3(8, 16), 256, 0, stream>>>(matrix, QQ, fcwT, QQ, M2, HH, QQ, HH, QQ, nullptr);
    mb_kernel<<<QQ, 256, 0, stream>>>(matrix, fc_b, mb);

    xg_kernel<<<BL, 256, 0, stream>>>(Aq, Bqa, Cqa, Dq, qint, qaint, pidf, xg);

    gru_persist<<<GBLK, 512, 0, stream>>>(xg, w_hh, b_hh, hA, gruT2, cells);

    mval_kernel<<<LL, 256, 0, stream>>>(gruT2, M2, mb, qint, mval);
    stats_kernel<<<BB, 256, 0, stream>>>(qint, qaint, mval, mc, mi, nmc, aa);
    dina_kernel<<<BB, 256, 0, stream>>>(qint, qaint, mval, mc, mi, nmc, aa, preds);
    loss_kernel<<<50, 256, 0, stream>>>(preds, target, out, acc);
    final_kernel<<<1, 1, 0, stream>>>(acc, out);
}

// Round 4
// 1486.445 us; speedup vs baseline: 6.7872x; 1.8461x over previous
//
#include <hip/hip_runtime.h>
#include <hip/hip_bf16.h>
#include <math.h>

// Problem constants
#define BB 64
#define LL 200
#define NQ 1024
#define DD 256
#define HH 512
#define QQ 1024
#define G3 1536   // 3*H
#define BL 12800  // B*L
#define GBLK 256  // persistent GRU grid: 1 block/CU, all CUs active

// ---------------- workspace layout (in floats) ----------------
#define OFF_ACC   ((size_t)0)                    // [0]=creg_raw [1]=mse [2]=maskcnt
#define OFF_CELLS ((size_t)16)                   // 64 barrier cells, 64B apart (1024 uints)
#define OFF_HA    ((size_t)1056)                 // hA[2][512][64]
#define OFF_AQ    (OFF_HA + 65536)               // 1025*1536
#define OFF_DQ    (OFF_AQ + 1574400)
#define OFF_BQA   (OFF_DQ + 1574400)             // 2*1536
#define OFF_CQA   (OFF_BQA + 3072)
#define OFF_WSUM  (OFF_CQA + 3072)               // 1536*256
#define OFF_FCWT  (OFF_WSUM + 393216)            // 512*1024
#define OFF_M2    (OFF_FCWT + 524288)            // 1024*512
#define OFF_MB    (OFF_M2 + 524288)              // 1024
#define OFF_XG    (OFF_MB + 1024)                // xgT [t][g][b] (also temp M2 splitk parts)
#define OFF_GRUT  (OFF_XG + 19660800)            // [t][b][k]
#define OFF_QINT  (OFF_GRUT + 6553600)           // 12800 ints [B][L]
#define OFF_QAINT (OFF_QINT + 12800)
#define OFF_PIDF  (OFF_QAINT + 12800)
#define OFF_MVAL  (OFF_PIDF + 12800)
#define OFF_MC    (OFF_MVAL + 12800)
#define OFF_MI    (OFF_MC + 12800)
#define OFF_NMC   (OFF_MI + 12800)
#define OFF_AA    (OFF_NMC + 12800)
#define OFF_PREDS (OFF_AA + 12800)

__device__ __forceinline__ float wave_sum64(float v) {
    #pragma unroll
    for (int o = 32; o > 0; o >>= 1) v += __shfl_down(v, o, 64);
    return v;
}

// LLC-coherent (device-scope, relaxed => no L2 writeback/invalidate) helpers
__device__ __forceinline__ float llc_load(const float* p) {
    return __hip_atomic_load(p, __ATOMIC_RELAXED, __HIP_MEMORY_SCOPE_AGENT);
}
__device__ __forceinline__ void llc_store(float* p, float v) {
    __hip_atomic_store(p, v, __ATOMIC_RELAXED, __HIP_MEMORY_SCOPE_AGENT);
}

// -------- meta: q, qa, pid per (b,t); c_reg accumulation --------
__global__ __launch_bounds__(256) void prep_meta(
    const int* __restrict__ q_data, const int* __restrict__ qa_data,
    const int* __restrict__ pid_data, const float* __restrict__ diff_parm,
    int* __restrict__ qint, int* __restrict__ qaint, float* __restrict__ pidf,
    float* __restrict__ acc)
{
    int r = blockIdx.x * 256 + threadIdx.x;
    float pp = 0.f;
    if (r < BL) {
        int q = q_data[r];
        qint[r] = q;
        qaint[r] = (qa_data[r] - q) / NQ;
        float pid = diff_parm[pid_data[r]];
        pidf[r] = pid;
        pp = pid * pid;
    }
    pp = wave_sum64(pp);
    __shared__ float sm[4];
    int lane = threadIdx.x & 63, w = threadIdx.x >> 6;
    if (lane == 0) sm[w] = pp;
    __syncthreads();
    if (threadIdx.x == 0) atomicAdd(&acc[0], sm[0] + sm[1] + sm[2] + sm[3]);
}

// -------- wsum[g,d] = w_ih[g,d] + w_ih[g,256+d] --------
__global__ __launch_bounds__(256) void wsum_kernel(const float* __restrict__ w_ih,
                                                   float* __restrict__ wsum)
{
    int g = blockIdx.x, d = threadIdx.x;
    wsum[(size_t)g * DD + d] = w_ih[(size_t)g * 2 * DD + d] + w_ih[(size_t)g * 2 * DD + DD + d];
}

// -------- transpose [R,C] -> [C,R] --------
__global__ __launch_bounds__(256) void transpose_kernel(const float* __restrict__ in,
                                                        float* __restrict__ out, int R, int C)
{
    __shared__ float tile[32][33];
    int r0 = blockIdx.y * 32, c0 = blockIdx.x * 32;
    int tx = threadIdx.x & 31, ty = threadIdx.x >> 5;
    #pragma unroll
    for (int i = 0; i < 32; i += 8) {
        int r = r0 + ty + i, c = c0 + tx;
        if (r < R && c < C) tile[ty + i][tx] = in[(size_t)r * C + c];
    }
    __syncthreads();
    #pragma unroll
    for (int i = 0; i < 32; i += 8) {
        int c = c0 + ty + i, r = r0 + tx;
        if (c < C && r < R) out[(size_t)c * R + r] = tile[tx][ty + i];
    }
}

// -------- dual-batched NT GEMM (two independent problems, z picks) --------
__global__ __launch_bounds__(256) void gemm_nt_dual(
    const float* __restrict__ A0, const float* __restrict__ A1, int lda,
    const float* __restrict__ B0, const float* __restrict__ B1, int ldb0, int ldb1,
    float* __restrict__ C0, float* __restrict__ C1, int ldc,
    int M, int N, int K,
    const float* __restrict__ bias0, const float* __restrict__ bias1)
{
    const int z = blockIdx.z;
    const float* A = z ? A1 : A0;
    const float* B = z ? B1 : B0;
    float* C = z ? C1 : C0;
    const int ldb = z ? ldb1 : ldb0;
    const float* bias = z ? bias1 : bias0;

    __shared__ float As[16][65];
    __shared__ float Bs[16][65];
    const int bm = blockIdx.y * 64, bn = blockIdx.x * 64;
    const int tid = threadIdx.x;
    const int tx = tid & 15, ty = tid >> 4;
    const int mm = tid >> 4, kk = tid & 15;
    float acc[4][4] = {};
    float ar[4], br[4];
    #pragma unroll
    for (int i = 0; i < 4; ++i) {
        int m = bm + mm + 16 * i;
        ar[i] = (m < M) ? A[(size_t)m * lda + kk] : 0.f;
        int n = bn + mm + 16 * i;
        br[i] = (n < N) ? B[(size_t)n * ldb + kk] : 0.f;
    }
    for (int k0 = 0; k0 < K; k0 += 16) {
        #pragma unroll
        for (int i = 0; i < 4; ++i) { As[kk][mm + 16 * i] = ar[i]; Bs[kk][mm + 16 * i] = br[i]; }
        __syncthreads();
        int kn = k0 + 16;
        if (kn < K) {
            #pragma unroll
            for (int i = 0; i < 4; ++i) {
                int m = bm + mm + 16 * i;
                ar[i] = (m < M) ? A[(size_t)m * lda + kn + kk] : 0.f;
                int n = bn + mm + 16 * i;
                br[i] = (n < N) ? B[(size_t)n * ldb + kn + kk] : 0.f;
            }
        }
        #pragma unroll
        for (int kq = 0; kq < 16; ++kq) {
            float a[4], b[4];
            #pragma unroll
            for (int i = 0; i < 4; ++i) a[i] = As[kq][ty * 4 + i];
            #pragma unroll
            for (int j = 0; j < 4; ++j) b[j] = Bs[kq][tx * 4 + j];
            #pragma unroll
            for (int i = 0; i < 4; ++i)
                #pragma unroll
                for (int j = 0; j < 4; ++j) acc[i][j] += a[i] * b[j];
        }
        __syncthreads();
    }
    #pragma unroll
    for (int i = 0; i < 4; ++i) {
        int m = bm + ty * 4 + i;
        if (m >= M) continue;
        #pragma unroll
        for (int j = 0; j < 4; ++j) {
            int n = bn + tx * 4 + j;
            if (n >= N) continue;
            C[(size_t)m * ldc + n] = acc[i][j] + (bias ? bias[n] : 0.f);
        }
    }
}

// -------- split-K NT GEMM: Cp[z] = A[:, zK4:(z+1)K4] . B[:, same]^T --------
__global__ __launch_bounds__(256) void gemm_nt_splitk(
    const float* __restrict__ Ain, int lda,
    const float* __restrict__ Bin, int ldb,
    float* __restrict__ Cp, int ldc,
    int M, int N, int K4)
{
    const int z = blockIdx.z;
    const float* A = Ain + (size_t)z * K4;
    const float* B = Bin + (size_t)z * K4;
    float* C = Cp + (size_t)z * M * ldc;

    __shared__ float As[16][65];
    __shared__ float Bs[16][65];
    const int bm = blockIdx.y * 64, bn = blockIdx.x * 64;
    const int tid = threadIdx.x;
    const int tx = tid & 15, ty = tid >> 4;
    const int mm = tid >> 4, kk = tid & 15;
    float acc[4][4] = {};
    float ar[4], br[4];
    #pragma unroll
    for (int i = 0; i < 4; ++i) {
        int m = bm + mm + 16 * i;
        ar[i] = (m < M) ? A[(size_t)m * lda + kk] : 0.f;
        int n = bn + mm + 16 * i;
        br[i] = (n < N) ? B[(size_t)n * ldb + kk] : 0.f;
    }
    for (int k0 = 0; k0 < K4; k0 += 16) {
        #pragma unroll
        for (int i = 0; i < 4; ++i) { As[kk][mm + 16 * i] = ar[i]; Bs[kk][mm + 16 * i] = br[i]; }
        __syncthreads();
        int kn = k0 + 16;
        if (kn < K4) {
            #pragma unroll
            for (int i = 0; i < 4; ++i) {
                int m = bm + mm + 16 * i;
                ar[i] = (m < M) ? A[(size_t)m * lda + kn + kk] : 0.f;
                int n = bn + mm + 16 * i;
                br[i] = (n < N) ? B[(size_t)n * ldb + kn + kk] : 0.f;
            }
        }
        #pragma unroll
        for (int kq = 0; kq < 16; ++kq) {
            float a[4], b[4];
            #pragma unroll
            for (int i = 0; i < 4; ++i) a[i] = As[kq][ty * 4 + i];
            #pragma unroll
            for (int j = 0; j < 4; ++j) b[j] = Bs[kq][tx * 4 + j];
            #pragma unroll
            for (int i = 0; i < 4; ++i)
                #pragma unroll
                for (int j = 0; j < 4; ++j) acc[i][j] += a[i] * b[j];
        }
        __syncthreads();
    }
    #pragma unroll
    for (int i = 0; i < 4; ++i) {
        int m = bm + ty * 4 + i;
        if (m >= M) continue;
        #pragma unroll
        for (int j = 0; j < 4; ++j) {
            int n = bn + tx * 4 + j;
            if (n >= N) continue;
            C[(size_t)m * ldc + n] = acc[i][j];
        }
    }
}

__global__ __launch_bounds__(256) void reduce4_kernel(const float* __restrict__ p,
                                                      float* __restrict__ o, int n)
{
    int i = blockIdx.x * 256 + threadIdx.x;
    if (i < n) o[i] = p[i] + p[n + i] + p[2 * n + i] + p[3 * n + i];
}

// -------- mb[k] = sum_q matrix[k,q]*fc_b[q] --------
__global__ __launch_bounds__(256) void mb_kernel(const float* __restrict__ matrix,
                                                 const float* __restrict__ fc_b,
                                                 float* __restrict__ mb)
{
    int k = blockIdx.x;
    float s = 0.f;
    for (int q = threadIdx.x; q < QQ; q += 256) s += matrix[(size_t)k * QQ + q] * fc_b[q];
    s = wave_sum64(s);
    __shared__ float sm[4];
    int lane = threadIdx.x & 63, w = threadIdx.x >> 6;
    if (lane == 0) sm[w] = s;
    __syncthreads();
    if (threadIdx.x == 0) mb[k] = sm[0] + sm[1] + sm[2] + sm[3];
}

// -------- fused xg gather + transpose: xgT[t][g][b] --------
__global__ __launch_bounds__(512) void xgt_kernel(
    const float* __restrict__ Aq, const float* __restrict__ Bqa,
    const float* __restrict__ Cqa, const float* __restrict__ Dq,
    const int* __restrict__ qint, const int* __restrict__ qaint,
    const float* __restrict__ pidf, float* __restrict__ xgT)
{
    const int t = blockIdx.x;
    __shared__ float tile[64][129];
    __shared__ int qs[BB];
    __shared__ int qas[BB];
    __shared__ float ps[BB];
    const int tid = threadIdx.x;
    if (tid < BB) {
        qs[tid] = qint[tid * LL + t];
        qas[tid] = qaint[tid * LL + t];
        ps[tid] = pidf[tid * LL + t];
    }
    __syncthreads();
    for (int g0 = 0; g0 < G3; g0 += 128) {
        #pragma unroll
        for (int it = 0; it < 16; ++it) {
            int idx = it * 512 + tid;
            int b = idx >> 7, gg = idx & 127;
            int g = g0 + gg;
            int q = qs[b], qa = qas[b];
            float pid = ps[b];
            tile[b][gg] = Aq[(size_t)q * G3 + g] + Bqa[(size_t)qa * G3 + g]
                        + pid * (Cqa[(size_t)qa * G3 + g] + Dq[(size_t)q * G3 + g]);
        }
        __syncthreads();
        #pragma unroll
        for (int it = 0; it < 16; ++it) {
            int idx = it * 512 + tid;
            int gg = idx >> 6, b = idx & 63;
            xgT[((size_t)t * G3 + g0 + gg) * BB + b] = tile[b][gg];
        }
        __syncthreads();
    }
}

// -------- persistent GRU: 256 blocks x 512 threads, 2 j-units/block --------
// Wave kq in [0,8): k-slice 64; lane = batch. w_hh rows (6) staged in LDS once.
// h ping-pong via relaxed agent-scope atomics (LLC-coherent, no L2 flush).
// Barrier: arrival add to 1 of 64 spread cells; wave 0 polls all 64 in parallel.
__global__ __launch_bounds__(512) void gru_persist(
    const float* __restrict__ xgT,     // [200][1536][64]
    const float* __restrict__ w_hh,    // [1536][512]
    const float* __restrict__ b_hh,    // [1536]
    float* __restrict__ hA,            // [2][512][64]
    float* __restrict__ gruT2,         // [200][64][512]
    unsigned int* __restrict__ cells)  // 64 cells, 64B apart
{
    __shared__ float ws[6][HH];        // 12 KB
    __shared__ float part[8][6][64];   // 12 KB
    __shared__ float sums[6][64];      // 1.5 KB
    const int tid = threadIdx.x;
    const int bid = blockIdx.x;
    const int j0 = bid * 2;

    for (int i = tid; i < 6 * HH; i += 512) {
        int r = i >> 9, k = i & 511;   // r = gate*2 + jq
        ws[r][k] = w_hh[((size_t)((r >> 1) * HH + j0 + (r & 1))) * HH + k];
    }
    const int wv = tid >> 6;           // 0..7
    const int lane = tid & 63;
    const int kb = wv * 64;
    const int jj = wv & 1;             // epilogue unit (tid<128)
    const int ej = j0 + jj;
    float bhr = 0.f, bhz = 0.f, bhn = 0.f;
    if (tid < 128) { bhr = b_hh[ej]; bhz = b_hh[HH + ej]; bhn = b_hh[2 * HH + ej]; }
    __syncthreads();

    int cur = 0;
    for (int t = 0; t < LL; ++t) {
        const float* hcur = hA + (size_t)cur * (HH * BB);
        float a0 = 0.f, a1 = 0.f, a2 = 0.f, a3 = 0.f, a4 = 0.f, a5 = 0.f;
        const float* hbase = hcur + (size_t)kb * BB + lane;
        #pragma unroll 4
        for (int c = 0; c < 16; ++c) {
            int k = kb + c * 4;
            float h0 = llc_load(hbase + (size_t)(c * 4 + 0) * BB);
            float h1 = llc_load(hbase + (size_t)(c * 4 + 1) * BB);
            float h2 = llc_load(hbase + (size_t)(c * 4 + 2) * BB);
            float h3 = llc_load(hbase + (size_t)(c * 4 + 3) * BB);
            {
                const float4 w0 = *(const float4*)&ws[0][k];
                a0 += w0.x * h0 + w0.y * h1 + w0.z * h2 + w0.w * h3;
                const float4 w1 = *(const float4*)&ws[1][k];
                a1 += w1.x * h0 + w1.y * h1 + w1.z * h2 + w1.w * h3;
                const float4 w2 = *(const float4*)&ws[2][k];
                a2 += w2.x * h0 + w2.y * h1 + w2.z * h2 + w2.w * h3;
                const float4 w3 = *(const float4*)&ws[3][k];
                a3 += w3.x * h0 + w3.y * h1 + w3.z * h2 + w3.w * h3;
                const float4 w4 = *(const float4*)&ws[4][k];
                a4 += w4.x * h0 + w4.y * h1 + w4.z * h2 + w4.w * h3;
                const float4 w5 = *(const float4*)&ws[5][k];
                a5 += w5.x * h0 + w5.y * h1 + w5.z * h2 + w5.w * h3;
            }
        }
        part[wv][0][lane] = a0; part[wv][1][lane] = a1; part[wv][2][lane] = a2;
        part[wv][3][lane] = a3; part[wv][4][lane] = a4; part[wv][5][lane] = a5;
        // epilogue input prefetch (independent of the partials)
        float xr = 0.f, xz = 0.f, xn = 0.f, hprev = 0.f;
        if (tid < 128) {
            const float* xb = xgT + (size_t)t * G3 * BB;
            xr = xb[(size_t)(0 * HH + ej) * BB + lane];
            xz = xb[(size_t)(1 * HH + ej) * BB + lane];
            xn = xb[(size_t)(2 * HH + ej) * BB + lane];
            hprev = llc_load(hcur + (size_t)ej * BB + lane);
        }
        __syncthreads();
        if (tid < 384) {
            int r = tid >> 6, b = tid & 63;
            sums[r][b] = part[0][r][b] + part[1][r][b] + part[2][r][b] + part[3][r][b]
                       + part[4][r][b] + part[5][r][b] + part[6][r][b] + part[7][r][b];
        }
        __syncthreads();
        if (tid < 128) {
            float sr = sums[jj][lane], sz = sums[2 + jj][lane], sn = sums[4 + jj][lane];
            float rg = 1.f / (1.f + expf(-(xr + sr + bhr)));
            float zg = 1.f / (1.f + expf(-(xz + sz + bhz)));
            float ng = tanhf(xn + rg * (sn + bhn));
            float hn = (1.f - zg) * ng + zg * hprev;
            llc_store(hA + (size_t)(cur ^ 1) * (HH * BB) + (size_t)ej * BB + lane, hn);
            gruT2[((size_t)t * BB + lane) * HH + ej] = hn;
        }
        __syncthreads();   // drains vmcnt: h stores LLC-visible before arrival
        if (tid == 0)
            __hip_atomic_fetch_add(&cells[(bid & 63) * 16], 1u,
                                   __ATOMIC_RELAXED, __HIP_MEMORY_SCOPE_AGENT);
        if (tid < 64) {    // wave 0: parallel poll, butterfly sum
            const unsigned want = (unsigned)(t + 1) * GBLK;
            for (;;) {
                unsigned v = __hip_atomic_load(&cells[lane * 16],
                                               __ATOMIC_RELAXED, __HIP_MEMORY_SCOPE_AGENT);
                #pragma unroll
                for (int o = 32; o > 0; o >>= 1) v += __shfl_xor((int)v, o, 64);
                if (v >= want) break;
                __builtin_amdgcn_s_sleep(2);
            }
        }
        __syncthreads();
        cur ^= 1;
    }
}

// -------- mvals[b,t] = threshold( dot(h_t, M2[q-1]) + mb[q-1] ) --------
__global__ __launch_bounds__(256) void mval_kernel(
    const float* __restrict__ gruT2,   // [200][64][512]
    const float* __restrict__ M2,      // [1024][512]
    const float* __restrict__ mb,
    const int* __restrict__ qint,      // [B][L]
    float* __restrict__ mval)          // [B][L]
{
    int t = blockIdx.x;
    int wave = threadIdx.x >> 6, l = threadIdx.x & 63;
    for (int ii = 0; ii < 16; ++ii) {
        int b = wave * 16 + ii;
        int q = qint[b * LL + t] - 1;
        const float4* hp = (const float4*)(gruT2 + ((size_t)t * BB + b) * HH);
        const float4* mp = (const float4*)(M2 + (size_t)q * HH);
        float4 h0 = hp[l], m0 = mp[l];
        float4 h1 = hp[64 + l], m1 = mp[64 + l];
        float acc = h0.x * m0.x + h0.y * m0.y + h0.z * m0.z + h0.w * m0.w
                  + h1.x * m1.x + h1.y * m1.y + h1.z * m1.z + h1.w * m1.w;
        acc = wave_sum64(acc);
        if (l == 0) {
            float s = acc + mb[q];
            mval[b * LL + t] = (s >= 0.4f) ? 1.0f : s;
        }
    }
}

// -------- per-(b,t) counting statistics --------
__global__ __launch_bounds__(256) void stats_kernel(
    const int* __restrict__ qint, const int* __restrict__ qaint,
    const float* __restrict__ mval,
    float* __restrict__ mc, float* __restrict__ mi,
    float* __restrict__ nmc, float* __restrict__ aa)
{
    int b = blockIdx.x, tid = threadIdx.x;
    __shared__ int qs[LL];
    __shared__ int qas[LL];
    __shared__ float mv[LL];
    if (tid < LL) {
        qs[tid] = qint[b * LL + tid];
        qas[tid] = qaint[b * LL + tid];
        mv[tid] = mval[b * LL + tid];
    }
    __syncthreads();
    int t = tid;
    if (t < LL) {
        int qt = qs[t];
        float smc = 0.f, smi = 0.f, snmc = 0.f, saa = 0.f;
        for (int k = 0; k <= t; ++k) {
            if (qs[k] == qt) {
                saa += 1.f;
                if (k < t) {
                    float mk = (mv[k] == 1.f) ? 1.f : 0.f;
                    float nk = (mv[k] == 0.f) ? 1.f : 0.f;
                    float a1 = (qas[k] == 1) ? 1.f : 0.f;
                    smc += a1 * mk;
                    smi += (1.f - a1) * mk;
                    snmc += (1.f - a1) * nk;
                }
            }
        }
        mc[b * LL + t] = smc;
        mi[b * LL + t] = smi;
        nmc[b * LL + t] = snmc;
        aa[b * LL + t] = saa;
    }
}

// -------- sequential DINA scan per batch --------
__global__ __launch_bounds__(256) void dina_kernel(
    const int* __restrict__ qint, const int* __restrict__ qaint,
    const float* __restrict__ mval,
    const float* __restrict__ mc, const float* __restrict__ mi,
    const float* __restrict__ nmc, const float* __restrict__ aa,
    float* __restrict__ preds)
{
    int b = blockIdx.x, tid = threadIdx.x;
    __shared__ float guess[QQ], slip[QQ];
    __shared__ float s_m[LL], s_mc[LL], s_mi[LL], s_nmc[LL], s_aa[LL];
    __shared__ int s_i[LL], s_qa[LL];
    for (int i = tid; i < QQ; i += 256) { guess[i] = 0.f; slip[i] = 0.f; }
    if (tid < LL) {
        s_m[tid] = mval[b * LL + tid];
        s_mc[tid] = mc[b * LL + tid];
        s_mi[tid] = mi[b * LL + tid];
        s_nmc[tid] = nmc[b * LL + tid];
        s_aa[tid] = aa[b * LL + tid];
        s_i[tid] = qint[b * LL + tid] - 1;
        s_qa[tid] = qaint[b * LL + tid];
    }
    __syncthreads();
    if (tid == 0) {
        for (int t = 0; t < LL; ++t) {
            int i = s_i[t];
            float m = s_m[t];
            int qa = s_qa[t];
            float aat = s_aa[t];
            float g_upd = (m == 1.f) ? s_mc[t] / aat
                          : ((qa == 0) ? 1.f - s_nmc[t] / aat : s_nmc[t] / aat);
            bool us = (m == 1.f) && (qa == 0);
            float ng = us ? guess[i] : g_upd;
            float ns = us ? s_mi[t] / aat : slip[i];
            guess[i] = ng;
            slip[i] = ns;
            preds[b * LL + t] = (1.f - ns) * (m * ng + (1.f - ns) * (1.f - m));
        }
    }
}

// -------- masked MSE + sigmoid outputs --------
__global__ __launch_bounds__(256) void loss_kernel(
    const float* __restrict__ preds, const float* __restrict__ target,
    float* __restrict__ out, float* __restrict__ acc)
{
    int r = blockIdx.x * 256 + threadIdx.x;
    float lm = 0.f, lc = 0.f;
    if (r < BL) {
        float p = preds[r], lab = target[r];
        float msk = (lab > -0.9f) ? 1.f : 0.f;
        float d = p - lab;
        lm = d * d * msk;
        lc = msk;
        out[1 + r] = 1.f / (1.f + expf(-p));
    }
    lm = wave_sum64(lm);
    lc = wave_sum64(lc);
    __shared__ float sm[4], sc[4];
    int lane = threadIdx.x & 63, w = threadIdx.x >> 6;
    if (lane == 0) { sm[w] = lm; sc[w] = lc; }
    __syncthreads();
    if (threadIdx.x == 0) {
        atomicAdd(&acc[1], sm[0] + sm[1] + sm[2] + sm[3]);
        atomicAdd(&acc[2], sc[0] + sc[1] + sc[2] + sc[3]);
    }
}

__global__ void final_kernel(const float* __restrict__ acc, float* __restrict__ out)
{
    out[0] = acc[1] + acc[0] * 1e-5f;
    out[1 + BL] = acc[2];
}

extern "C" void kernel_launch(void* const* d_in, const int* in_sizes, int n_in,
                              void* d_out, int out_size, void* d_ws, size_t ws_size,
                              hipStream_t stream) {
    const int* q_data = (const int*)d_in[0];
    const int* qa_data = (const int*)d_in[1];
    const int* pid_data = (const int*)d_in[2];
    const float* matrix = (const float*)d_in[3];
    const float* target = (const float*)d_in[4];
    const float* q_emb = (const float*)d_in[5];
    const float* qa_emb = (const float*)d_in[6];
    const float* q_emb_diff = (const float*)d_in[7];
    const float* qa_emb_diff = (const float*)d_in[8];
    const float* diff_parm = (const float*)d_in[9];
    const float* w_ih = (const float*)d_in[10];
    const float* w_hh = (const float*)d_in[11];
    const float* b_ih = (const float*)d_in[12];
    const float* b_hh = (const float*)d_in[13];
    const float* fc_w = (const float*)d_in[14];
    const float* fc_b = (const float*)d_in[15];
    float* out = (float*)d_out;
    float* W = (float*)d_ws;

    float* acc = W + OFF_ACC;
    unsigned int* cells = (unsigned int*)(W + OFF_CELLS);
    float* hA = W + OFF_HA;
    float* Aq = W + OFF_AQ;
    float* Dq = W + OFF_DQ;
    float* Bqa = W + OFF_BQA;
    float* Cqa = W + OFF_CQA;
    float* wsum = W + OFF_WSUM;
    float* fcwT = W + OFF_FCWT;
    float* M2 = W + OFF_M2;
    float* mb = W + OFF_MB;
    float* xgT = W + OFF_XG;
    float* m2parts = W + OFF_XG;       // temp: reused before xgT is written
    float* gruT2 = W + OFF_GRUT;
    int* qint = (int*)(W + OFF_QINT);
    int* qaint = (int*)(W + OFF_QAINT);
    float* pidf = W + OFF_PIDF;
    float* mval = W + OFF_MVAL;
    float* mc = W + OFF_MC;
    float* mi = W + OFF_MI;
    float* nmc = W + OFF_NMC;
    float* aa = W + OFF_AA;
    float* preds = W + OFF_PREDS;

    // zero accumulators + barrier cells + both h buffers (contiguous at ws start)
    hipMemsetAsync(W, 0, (OFF_HA + 2 * HH * BB) * sizeof(float), stream);

    prep_meta<<<50, 256, 0, stream>>>(q_data, qa_data, pid_data, diff_parm,
                                      qint, qaint, pidf, acc);
    wsum_kernel<<<G3, 256, 0, stream>>>(w_ih, wsum);
    transpose_kernel<<<dim3(16, 32), 256, 0, stream>>>(fc_w, fcwT, QQ, HH);

    // Bqa/Cqa batched
    gemm_nt_dual<<<dim3(24, 1, 2), 256, 0, stream>>>(
        qa_emb, qa_emb_diff, DD, w_ih, w_ih, 2 * DD, 2 * DD,
        Bqa, Cqa, G3, 2, G3, DD, b_ih, nullptr);
    // Aq/Dq batched
    gemm_nt_dual<<<dim3(24, 17, 2), 256, 0, stream>>>(
        q_emb, q_emb_diff, DD, wsum, w_ih + DD, DD, 2 * DD,
        Aq, Dq, G3, NQ + 1, G3, DD, nullptr, nullptr);
    // M2 = matrix . fc_w  (split-K x4 into temp region, then reduce)
    gemm_nt_splitk<<<dim3(8, 16, 4), 256, 0, stream>>>(
        matrix, QQ, fcwT, QQ, m2parts, HH, QQ, HH, QQ / 4);
    reduce4_kernel<<<2048, 256, 0, stream>>>(m2parts, M2, QQ * HH);
    mb_kernel<<<QQ, 256, 0, stream>>>(matrix, fc_b, mb);

    // xgT gather+transpose (overwrites the m2parts temp region)
    xgt_kernel<<<LL, 512, 0, stream>>>(Aq, Bqa, Cqa, Dq, qint, qaint, pidf, xgT);

    gru_persist<<<GBLK, 512, 0, stream>>>(xgT, w_hh, b_hh, hA, gruT2, cells);

    mval_kernel<<<LL, 256, 0, stream>>>(gruT2, M2, mb, qint, mval);
    stats_kernel<<<BB, 256, 0, stream>>>(qint, qaint, mval, mc, mi, nmc, aa);
    dina_kernel<<<BB, 256, 0, stream>>>(qint, qaint, mval, mc, mi, nmc, aa, preds);
    loss_kernel<<<50, 256, 0, stream>>>(preds, target, out, acc);
    final_kernel<<<1, 1, 0, stream>>>(acc, out);
}